// Round 2
// baseline (433.598 us; speedup 1.0000x reference)
//
#include <hip/hip_runtime.h>

// Problem constants (fixed by the reference's setup_inputs)
#define BATCH   256
#define N_PER   4096
#define EMBED   16
#define HID     32
#define NOTE    64
#define LSTM_D  64
#define T_LEN   128
#define VOCAB   200
#define HSTR    (BATCH * HID)       // floats per slot row-group (tree-inner layout)

// ---------------------------------------------------------------------------
// meta header (ints)
#define MH_C0    0     // kind-0 leaf count (per tree)
#define MH_C1    1     // kind-1 ptr count
#define MH_CNT   2     // [2..6] internal count at level 1..5
#define MH_P     7     // total parents (internal levels 1..5 + root)
#define MH_PBASE 8     // [8..12] pidx base of level 1..5
// arrays
#define OFF_K0N   64
#define OFF_K0S   (OFF_K0N + N_PER)
#define OFF_K1N   (OFF_K0S + N_PER)
#define OFF_K1S   (OFF_K1N + N_PER)
#define OFF_PLIST (OFF_K1S + N_PER)
#define OFF_WSLOT (OFF_PLIST + N_PER)
#define OFF_COFF  (OFF_WSLOT + N_PER)    // N_PER+1 entries
// float regions (byte offsets in ws)
#define EAW_OFF     (1024 * 1024)        // [VOCAB][HID]
#define EBW_OFF     (EAW_OFF + VOCAB * HID * 4)
#define LA2_OFF     (EBW_OFF + VOCAB * HID * 4)   // leaf table A: (emb@W1a)@W2
#define LB2_OFF     (LA2_OFF + VOCAB * HID * 4)   // leaf table B: (emb@W1b)@W2
#define CC_OFF      (LB2_OFF + VOCAB * HID * 4)   // b1@W2 + b2   [HID]
#define ROOTSUM_OFF (1792 * 1024)        // [BATCH][HID]
#define H_OFF       (8ull * 1024 * 1024) // [N_PER slots][BATCH][HID]

#define RCHUNK 16

__device__ __forceinline__ unsigned long long shflup64(unsigned long long x, int off) {
    unsigned lo = (unsigned)(x & 0xffffffffull);
    unsigned hi = (unsigned)(x >> 32);
    lo = __shfl_up(lo, off, 64);
    hi = __shfl_up(hi, off, 64);
    return ((unsigned long long)hi << 32) | (unsigned long long)lo;
}

// ---------------------------------------------------------------------------
// Build (verified in prior session): bucket nodes (k0, k1, levels 1..5, root)
// with stable packed-u64 scans; parents ordered by level; slot = CSR position
// in parent's children block => each level's child-slot range is contiguous.
// R1: Hillis-Steele block scans replaced with wave-shfl scans (2 barriers per
// scan instead of 20); weight-table precompute (eaw/ebw/la2/lb2/cc) folded in.
// ---------------------------------------------------------------------------
__global__ __launch_bounds__(1024) void build_structure(
    const int* __restrict__ kind, const int* __restrict__ height,
    const int* __restrict__ parent, int* __restrict__ meta,
    const float* __restrict__ embedding,
    const float* __restrict__ leaf_w1, const float* __restrict__ leaf_b1,
    const float* __restrict__ leaf_w2, const float* __restrict__ leaf_b2,
    const float* __restrict__ node_w,
    float* __restrict__ eaw_g, float* __restrict__ ebw_g,
    float* __restrict__ la2, float* __restrict__ lb2, float* __restrict__ cc)
{
    __shared__ unsigned long long wlo[16], whi[16];
    __shared__ int wint[16];
    __shared__ int node2pidx[N_PER];   // 16 KB
    __shared__ int deg[N_PER];         // 16 KB
    __shared__ int sbases[8];
    __shared__ int stot[8];

    int t  = threadIdx.x;
    int i0 = 4 * t;
    int laneid = t & 63;
    int wid    = t >> 6;

    int myb[4];
    #pragma unroll
    for (int q = 0; q < 4; ++q) {
        int i = i0 + q;
        int hgt = height[i];
        int b;
        if (hgt > 0) { b = 1 + hgt; if (b > 7) b = 7; }   // levels 1..5 -> 2..6, root -> 7
        else b = (kind[i] == 0) ? 0 : 1;
        myb[q] = b;
    }
    unsigned long long clo = 0, chi = 0;
    #pragma unroll
    for (int q = 0; q < 4; ++q) {
        int b = myb[q];
        if (b < 4) clo += 1ull << (16 * b);
        else       chi += 1ull << (16 * (b - 4));
    }

    // dual u64 inclusive scan: wave-level shfl scan + wave-total combine
    unsigned long long a = clo, b64 = chi;
    #pragma unroll
    for (int off = 1; off < 64; off <<= 1) {
        unsigned long long ua = shflup64(a, off);
        unsigned long long ub = shflup64(b64, off);
        if (laneid >= off) { a += ua; b64 += ub; }
    }
    if (laneid == 63) { wlo[wid] = a; whi[wid] = b64; }
    __syncthreads();
    unsigned long long blo = 0, bhi = 0;
    for (int w = 0; w < wid; ++w) { blo += wlo[w]; bhi += whi[w]; }
    unsigned long long inc_lo = a + blo, inc_hi = b64 + bhi;
    if (t == 0) {
        unsigned long long tlo = 0, thi = 0;
        for (int w = 0; w < 16; ++w) { tlo += wlo[w]; thi += whi[w]; }
        stot[0] = (int)(tlo & 0xFFFF);         stot[1] = (int)((tlo >> 16) & 0xFFFF);
        stot[2] = (int)((tlo >> 32) & 0xFFFF); stot[3] = (int)((tlo >> 48) & 0xFFFF);
        stot[4] = (int)(thi & 0xFFFF);         stot[5] = (int)((thi >> 16) & 0xFFFF);
        stot[6] = (int)((thi >> 32) & 0xFFFF); stot[7] = (int)((thi >> 48) & 0xFFFF);
        int s = 0;
        for (int bb = 0; bb < 8; ++bb) { sbases[bb] = s; s += stot[bb]; }
        meta[MH_C0] = stot[0];
        meta[MH_C1] = stot[1];
        for (int l = 0; l < 5; ++l) meta[MH_CNT + l]   = stot[2 + l];
        for (int l = 0; l < 5; ++l) meta[MH_PBASE + l] = sbases[2 + l] - sbases[2];
        meta[MH_P] = (sbases[7] - sbases[2]) + stot[7];
    }
    __syncthreads();

    unsigned long long exlo = inc_lo - clo, exhi = inc_hi - chi;
    int mypos[4], mypidx[4];
    #pragma unroll
    for (int q = 0; q < 4; ++q) {
        int i = i0 + q, b = myb[q];
        int pos;
        if (b < 4) { pos = (int)((exlo >> (16 * b)) & 0xFFFF); exlo += 1ull << (16 * b); }
        else       { pos = (int)((exhi >> (16 * (b - 4))) & 0xFFFF); exhi += 1ull << (16 * (b - 4)); }
        mypos[q] = pos;
        int pidx = -1;
        if (b == 0)      meta[OFF_K0N + pos] = i;
        else if (b == 1) meta[OFF_K1N + pos] = i;
        else {
            pidx = (sbases[b] - sbases[2]) + pos;
            meta[OFF_PLIST + pidx] = i;
            node2pidx[i] = pidx;
        }
        mypidx[q] = pidx;
    }
    #pragma unroll
    for (int q = 0; q < 4; ++q) deg[i0 + q] = 0;
    __syncthreads();

    int par[4];
    #pragma unroll
    for (int q = 0; q < 4; ++q) {
        int i = i0 + q; par[q] = parent[i];
        if (i != 0) atomicAdd(&deg[node2pidx[par[q]]], 1);
    }
    __syncthreads();

    int d0 = deg[i0], d1 = deg[i0 + 1], d2 = deg[i0 + 2], d3 = deg[i0 + 3];
    int s4 = d0 + d1 + d2 + d3;

    // int inclusive scan: wave-level shfl scan + wave-total combine
    int vi = s4;
    #pragma unroll
    for (int off = 1; off < 64; off <<= 1) {
        int u = __shfl_up(vi, off, 64);
        if (laneid >= off) vi += u;
    }
    if (laneid == 63) wint[wid] = vi;
    __syncthreads();
    int bint = 0;
    for (int w = 0; w < wid; ++w) bint += wint[w];
    int incl = vi + bint;

    int ex = incl - s4;
    int o0 = ex, o1 = ex + d0, o2 = o1 + d1, o3 = o2 + d2;
    deg[i0] = o0; deg[i0 + 1] = o1; deg[i0 + 2] = o2; deg[i0 + 3] = o3;
    meta[OFF_COFF + i0]     = o0;
    meta[OFF_COFF + i0 + 1] = o1;
    meta[OFF_COFF + i0 + 2] = o2;
    meta[OFF_COFF + i0 + 3] = o3;
    if (t == 1023) meta[OFF_COFF + N_PER] = o3 + d3;
    __syncthreads();

    #pragma unroll
    for (int q = 0; q < 4; ++q) {
        int i = i0 + q; if (i == 0) continue;
        int slot = atomicAdd(&deg[node2pidx[par[q]]], 1);
        int b = myb[q];
        if (b == 0)      meta[OFF_K0S + mypos[q]] = slot;
        else if (b == 1) meta[OFF_K1S + mypos[q]] = slot;
        else             meta[OFF_WSLOT + mypidx[q]] = slot;
    }

    // ---- weight tables (independent of tree data; ~0.8M MACs on this CU) ----
    // eaw/ebw: emb@node_w[:16] / emb@node_w[16:32]
    // la2/lb2: (emb@leaf_w1[:16])@leaf_w2 / (emb@leaf_w1[16:32])@leaf_w2
    //   (leaf MLP is LINEAR: leaf_h = la2[ta] + lb2[tb] + (b1@W2 + b2))
    {
        int hw = t >> 5, ln = t & 31;
        for (int v = hw; v < VOCAB; v += 32) {
            const float* ev = embedding + v * EMBED;
            float ea = 0.f, eb = 0.f, t1a = 0.f, t1b = 0.f;
            #pragma unroll
            for (int k = 0; k < EMBED; ++k) {
                float e = ev[k];
                ea  += e * node_w[k * HID + ln];
                eb  += e * node_w[(EMBED + k) * HID + ln];
                t1a += e * leaf_w1[k * HID + ln];
                t1b += e * leaf_w1[(EMBED + k) * HID + ln];
            }
            eaw_g[v * HID + ln] = ea;
            ebw_g[v * HID + ln] = eb;
            float a2 = 0.f, b2v = 0.f;
            #pragma unroll
            for (int k = 0; k < HID; ++k) {
                float w2 = leaf_w2[k * HID + ln];
                a2  += __shfl(t1a, k, 32) * w2;
                b2v += __shfl(t1b, k, 32) * w2;
            }
            la2[v * HID + ln] = a2;
            lb2[v * HID + ln] = b2v;
        }
        if (t < HID) {
            float c = leaf_b2[t];
            #pragma unroll
            for (int k = 0; k < HID; ++k) c += leaf_b1[k] * leaf_w2[k * HID + t];
            cc[t] = c;
        }
    }
}

// ---------------------------------------------------------------------------
// Prep: leaf rows via precomputed tables (pure gather+store) and ptr rows
// computed directly from first_notes/lstm_out (tiny GEMVs, no intermediates).
// ---------------------------------------------------------------------------
__global__ __launch_bounds__(256) void prep_kernel(
    const int* __restrict__ meta,
    const int* __restrict__ tok_a, const int* __restrict__ tok_b,
    const int* __restrict__ ptr_time,
    const float* __restrict__ first_notes, const float* __restrict__ lstm_out,
    const float* __restrict__ la2, const float* __restrict__ lb2,
    const float* __restrict__ cc,
    const float* __restrict__ ptr_w, const float* __restrict__ ptr_b,
    float* __restrict__ h)
{
    int tid  = blockIdx.x * blockDim.x + threadIdx.x;
    int nthr = gridDim.x * blockDim.x;
    int lane = threadIdx.x & 31;
    int gid  = tid >> 5;
    int ngr  = nthr >> 5;

    // --- leaf rows: h = cc + la2[ta] + lb2[tb]  (tree-inner coalesced) ---
    {
        float ccv = cc[lane];
        int c0 = meta[MH_C0];
        const int* K0N = meta + OFF_K0N;
        const int* K0S = meta + OFF_K0S;
        int tot = c0 * BATCH;
        for (int i = gid; i < tot; i += ngr) {
            int j = i >> 8, tree = i & 255;
            int node = K0N[j], slot = K0S[j];
            int gn = tree * N_PER + node;
            int ta = tok_a[gn], tb = tok_b[gn];
            h[(size_t)slot * HSTR + tree * HID + lane] =
                ccv + la2[ta * HID + lane] + lb2[tb * HID + lane];
        }
    }

    // --- ptr rows: h = ptr_b + fn[tree]@Wp[0:64] + lstm[tree,tt]@Wp[64:128] ---
    {
        float pb = ptr_b[lane];
        int c1 = meta[MH_C1];
        const int* K1N = meta + OFF_K1N;
        const int* K1S = meta + OFF_K1S;
        int tot = c1 * BATCH;
        for (int i = gid; i < tot; i += ngr) {
            int j = i >> 8, tree = i & 255;
            int node = K1N[j], slot = K1S[j];
            int gn = tree * N_PER + node;
            int tt = ptr_time[gn];
            const float* fn = first_notes + (size_t)tree * NOTE;
            const float* lo = lstm_out + ((size_t)tree * T_LEN + tt) * LSTM_D;
            float v = pb;
            #pragma unroll
            for (int k = 0; k < NOTE; ++k)   v += fn[k] * ptr_w[k * HID + lane];
            #pragma unroll
            for (int k = 0; k < LSTM_D; ++k) v += lo[k] * ptr_w[(NOTE + k) * HID + lane];
            h[(size_t)slot * HSTR + tree * HID + lane] = v;
        }
    }
}

// ---------------------------------------------------------------------------
// Level pass (lvl = 0..4 for heights 1..5): for parents at this level,
//   h[wslot][tree] = relu(node_b + eaw[ta] + ebw[tb] + csum @ node_w[32:64])
// Children of the level form a contiguous slot range -> streaming reads.
// Work item = (tree-chunk, parent, tree-in-chunk) for L2 tok locality.
// ---------------------------------------------------------------------------
__global__ __launch_bounds__(256) void level_kernel(
    const int* __restrict__ meta,
    const int* __restrict__ tok_a, const int* __restrict__ tok_b,
    const float* __restrict__ eaw_g, const float* __restrict__ ebw_g,
    const float* __restrict__ node_w, const float* __restrict__ node_b,
    float* __restrict__ h, int lvl)
{
    int cnt = meta[MH_CNT + lvl];
    int pb  = meta[MH_PBASE + lvl];
    const int* PL = meta + OFF_PLIST;
    const int* WS = meta + OFF_WSLOT;
    const int* CO = meta + OFF_COFF;

    int lane = threadIdx.x & 31;
    int gid  = (blockIdx.x * blockDim.x + threadIdx.x) >> 5;
    int ngr  = (gridDim.x * blockDim.x) >> 5;

    float wc[HID];
    #pragma unroll
    for (int k = 0; k < HID; ++k) wc[k] = node_w[(2 * EMBED + k) * HID + lane];
    float nb = node_b[lane];

    int perchunk = cnt << 5;             // parents * 32 trees
    int tot = cnt * BATCH;
    for (int i = gid; i < tot; i += ngr) {
        int tchunk = i / perchunk;
        int r      = i - tchunk * perchunk;
        int rr     = r >> 5;
        int tree   = (tchunk << 5) + (r & 31);
        int pidx = pb + rr;
        int node = PL[pidx], wslot = WS[pidx];
        int e = CO[pidx], e1 = CO[pidx + 1];

        const float* hb = h + (size_t)tree * HID + lane;
        float s0 = 0.f, s1 = 0.f, s2 = 0.f, s3 = 0.f;
        int c = e;
        for (; c + 4 <= e1; c += 4) {
            s0 += hb[(size_t)(c)     * HSTR];
            s1 += hb[(size_t)(c + 1) * HSTR];
            s2 += hb[(size_t)(c + 2) * HSTR];
            s3 += hb[(size_t)(c + 3) * HSTR];
        }
        for (; c < e1; ++c) s0 += hb[(size_t)c * HSTR];
        float csum = (s0 + s1) + (s2 + s3);

        int gn = tree * N_PER + node;
        int ta = tok_a[gn], tb = tok_b[gn];
        float v = nb + eaw_g[ta * HID + lane] + ebw_g[tb * HID + lane];
        #pragma unroll
        for (int k = 0; k < HID; ++k) v += __shfl(csum, k, 32) * wc[k];
        v = fmaxf(v, 0.f);
        h[(size_t)wslot * HSTR + tree * HID + lane] = v;
    }
}

// ---------------------------------------------------------------------------
// Root gather: chunked coalesced partial sums -> atomicAdd rootsum[tree][hid]
// ---------------------------------------------------------------------------
__global__ __launch_bounds__(256) void root_gather_kernel(
    const int* __restrict__ meta, const float* __restrict__ h,
    float* __restrict__ rootsum)
{
    const int* CO = meta + OFF_COFF;
    int P = meta[MH_P];
    int e = CO[P - 1], e1 = CO[P];
    int n = e1 - e;
    int per = (n + RCHUNK - 1) / RCHUNK;

    int t = blockIdx.x * blockDim.x + threadIdx.x;   // RCHUNK*BATCH*HID threads
    int lane  = t & 31;
    int tree  = (t >> 5) & 255;
    int chunk = t >> 13;
    if (chunk >= RCHUNK) return;

    int s  = e + chunk * per;
    int en = s + per; if (en > e1) en = e1;
    if (s >= en) return;
    float sum = 0.f;
    for (int c = s; c < en; ++c)
        sum += h[(size_t)c * HSTR + tree * HID + lane];
    atomicAdd(&rootsum[tree * HID + lane], sum);
}

// ---------------------------------------------------------------------------
// Final: finish root h, FF head -> out[tree]
// ---------------------------------------------------------------------------
__global__ __launch_bounds__(256) void final_kernel(
    const int* __restrict__ meta,
    const int* __restrict__ tok_a, const int* __restrict__ tok_b,
    const float* __restrict__ eaw_g, const float* __restrict__ ebw_g,
    const float* __restrict__ rootsum,
    const float* __restrict__ node_w, const float* __restrict__ node_b,
    const float* __restrict__ ff_w1, const float* __restrict__ ff_b1,
    const float* __restrict__ ff_w2, const float* __restrict__ ff_b2,
    const float* __restrict__ tail_w, const float* __restrict__ tail_b,
    float* __restrict__ out)
{
    int tree = (blockIdx.x * blockDim.x + threadIdx.x) >> 5;
    int lane = threadIdx.x & 31;
    if (tree >= BATCH) return;

    float csum = rootsum[tree * HID + lane];
    int gn = tree * N_PER;   // root = node 0
    int ta = tok_a[gn], tb = tok_b[gn];
    float v = node_b[lane] + eaw_g[ta * HID + lane] + ebw_g[tb * HID + lane];
    #pragma unroll
    for (int k = 0; k < HID; ++k)
        v += __shfl(csum, k, 32) * node_w[(2 * EMBED + k) * HID + lane];
    v = fmaxf(v, 0.f);

    float f1 = ff_b1[lane];
    #pragma unroll
    for (int k = 0; k < HID; ++k) f1 += __shfl(v, k, 32) * ff_w1[k * HID + lane];
    float f2 = ff_b2[lane];
    #pragma unroll
    for (int k = 0; k < HID; ++k) f2 += __shfl(f1, k, 32) * ff_w2[k * HID + lane];

    float c2 = f2 * tail_w[lane];
    #pragma unroll
    for (int off = 16; off > 0; off >>= 1) c2 += __shfl_down(c2, off, 32);
    if (lane == 0) out[tree] = c2 + tail_b[0];
}

extern "C" void kernel_launch(void* const* d_in, const int* in_sizes, int n_in,
                              void* d_out, int out_size, void* d_ws, size_t ws_size,
                              hipStream_t stream) {
    const int*   kind        = (const int*)d_in[0];
    const int*   height      = (const int*)d_in[1];
    const int*   parent      = (const int*)d_in[2];
    const int*   tok_a       = (const int*)d_in[3];
    const int*   tok_b       = (const int*)d_in[4];
    const int*   ptr_time    = (const int*)d_in[5];
    const float* first_notes = (const float*)d_in[6];
    const float* lstm_out    = (const float*)d_in[7];
    const float* embedding   = (const float*)d_in[8];
    const float* leaf_w1     = (const float*)d_in[9];
    const float* leaf_b1     = (const float*)d_in[10];
    const float* leaf_w2     = (const float*)d_in[11];
    const float* leaf_b2     = (const float*)d_in[12];
    const float* node_w      = (const float*)d_in[13];
    const float* node_b      = (const float*)d_in[14];
    const float* ptr_w       = (const float*)d_in[15];
    const float* ptr_b       = (const float*)d_in[16];
    const float* ff_w1       = (const float*)d_in[17];
    const float* ff_b1       = (const float*)d_in[18];
    const float* ff_w2       = (const float*)d_in[19];
    const float* ff_b2       = (const float*)d_in[20];
    const float* tail_w      = (const float*)d_in[21];
    const float* tail_b      = (const float*)d_in[22];

    char* ws = (char*)d_ws;
    int*   meta    = (int*)ws;
    float* eaw_g   = (float*)(ws + EAW_OFF);
    float* ebw_g   = (float*)(ws + EBW_OFF);
    float* la2     = (float*)(ws + LA2_OFF);
    float* lb2     = (float*)(ws + LB2_OFF);
    float* cc      = (float*)(ws + CC_OFF);
    float* rootsum = (float*)(ws + ROOTSUM_OFF);
    float* h       = (float*)(ws + H_OFF);

    hipMemsetAsync(rootsum, 0, BATCH * HID * sizeof(float), stream);

    build_structure<<<1, 1024, 0, stream>>>(
        kind, height, parent, meta,
        embedding, leaf_w1, leaf_b1, leaf_w2, leaf_b2, node_w,
        eaw_g, ebw_g, la2, lb2, cc);

    prep_kernel<<<2048, 256, 0, stream>>>(
        meta, tok_a, tok_b, ptr_time, first_notes, lstm_out,
        la2, lb2, cc, ptr_w, ptr_b, h);

    for (int lvl = 0; lvl < 5; ++lvl) {
        level_kernel<<<4096, 256, 0, stream>>>(
            meta, tok_a, tok_b, eaw_g, ebw_g, node_w, node_b, h, lvl);
    }

    root_gather_kernel<<<(RCHUNK * BATCH * HID) / 256, 256, 0, stream>>>(
        meta, h, rootsum);

    final_kernel<<<32, 256, 0, stream>>>(
        meta, tok_a, tok_b, eaw_g, ebw_g, rootsum, node_w, node_b,
        ff_w1, ff_b1, ff_w2, ff_b2, tail_w, tail_b, (float*)d_out);
}

// Round 3
// 401.206 us; speedup vs baseline: 1.0807x; 1.0807x over previous
//
#include <hip/hip_runtime.h>

// Problem constants (fixed by the reference's setup_inputs)
#define BATCH   256
#define N_PER   4096
#define EMBED   16
#define HID     32
#define NOTE    64
#define LSTM_D  64
#define T_LEN   128
#define VOCAB   200
#define HSTR    (BATCH * HID)       // floats per slot row-group (tree-inner layout)

// ---------------------------------------------------------------------------
// meta header (ints)
#define MH_C0    0     // kind-0 leaf count (per tree)
#define MH_C1    1     // kind-1 ptr count
#define MH_CNT   2     // [2..6] internal count at level 1..5
#define MH_P     7     // total parents (internal levels 1..5 + root)
#define MH_PBASE 8     // [8..12] pidx base of level 1..5
// arrays
#define OFF_K0N   64
#define OFF_K0S   (OFF_K0N + N_PER)
#define OFF_K1N   (OFF_K0S + N_PER)
#define OFF_K1S   (OFF_K1N + N_PER)
#define OFF_PLIST (OFF_K1S + N_PER)
#define OFF_WSLOT (OFF_PLIST + N_PER)
#define OFF_COFF  (OFF_WSLOT + N_PER)    // N_PER+1 entries
// float regions (byte offsets in ws)
#define EAW_OFF     (1024 * 1024)        // [VOCAB][HID]
#define EBW_OFF     (EAW_OFF + VOCAB * HID * 4)
#define LA2_OFF     (EBW_OFF + VOCAB * HID * 4)   // leaf table A: (emb@W1a)@W2
#define LB2_OFF     (LA2_OFF + VOCAB * HID * 4)   // leaf table B: (emb@W1b)@W2
#define CC_OFF      (LB2_OFF + VOCAB * HID * 4)   // b1@W2 + b2   [HID]
#define H_OFF       (8ull * 1024 * 1024) // [N_PER slots][BATCH][HID]

__device__ __forceinline__ unsigned long long shflup64(unsigned long long x, int off) {
    unsigned lo = (unsigned)(x & 0xffffffffull);
    unsigned hi = (unsigned)(x >> 32);
    lo = __shfl_up(lo, off, 64);
    hi = __shfl_up(hi, off, 64);
    return ((unsigned long long)hi << 32) | (unsigned long long)lo;
}

// ---------------------------------------------------------------------------
// Build: bucket nodes (k0, k1, levels 1..5, root) with stable packed-u64 wave
// scans; parents ordered by level; slot = CSR position in parent's children
// block => each level's child-slot range is contiguous. Weight tables folded.
// ---------------------------------------------------------------------------
__global__ __launch_bounds__(1024) void build_structure(
    const int* __restrict__ kind, const int* __restrict__ height,
    const int* __restrict__ parent, int* __restrict__ meta,
    const float* __restrict__ embedding,
    const float* __restrict__ leaf_w1, const float* __restrict__ leaf_b1,
    const float* __restrict__ leaf_w2, const float* __restrict__ leaf_b2,
    const float* __restrict__ node_w,
    float* __restrict__ eaw_g, float* __restrict__ ebw_g,
    float* __restrict__ la2, float* __restrict__ lb2, float* __restrict__ cc)
{
    __shared__ unsigned long long wlo[16], whi[16];
    __shared__ int wint[16];
    __shared__ int node2pidx[N_PER];   // 16 KB
    __shared__ int deg[N_PER];         // 16 KB
    __shared__ int sbases[8];
    __shared__ int stot[8];

    int t  = threadIdx.x;
    int i0 = 4 * t;
    int laneid = t & 63;
    int wid    = t >> 6;

    int myb[4];
    #pragma unroll
    for (int q = 0; q < 4; ++q) {
        int i = i0 + q;
        int hgt = height[i];
        int b;
        if (hgt > 0) { b = 1 + hgt; if (b > 7) b = 7; }   // levels 1..5 -> 2..6, root -> 7
        else b = (kind[i] == 0) ? 0 : 1;
        myb[q] = b;
    }
    unsigned long long clo = 0, chi = 0;
    #pragma unroll
    for (int q = 0; q < 4; ++q) {
        int b = myb[q];
        if (b < 4) clo += 1ull << (16 * b);
        else       chi += 1ull << (16 * (b - 4));
    }

    // dual u64 inclusive scan: wave-level shfl scan + wave-total combine
    unsigned long long a = clo, b64 = chi;
    #pragma unroll
    for (int off = 1; off < 64; off <<= 1) {
        unsigned long long ua = shflup64(a, off);
        unsigned long long ub = shflup64(b64, off);
        if (laneid >= off) { a += ua; b64 += ub; }
    }
    if (laneid == 63) { wlo[wid] = a; whi[wid] = b64; }
    __syncthreads();
    unsigned long long blo = 0, bhi = 0;
    for (int w = 0; w < wid; ++w) { blo += wlo[w]; bhi += whi[w]; }
    unsigned long long inc_lo = a + blo, inc_hi = b64 + bhi;
    if (t == 0) {
        unsigned long long tlo = 0, thi = 0;
        for (int w = 0; w < 16; ++w) { tlo += wlo[w]; thi += whi[w]; }
        stot[0] = (int)(tlo & 0xFFFF);         stot[1] = (int)((tlo >> 16) & 0xFFFF);
        stot[2] = (int)((tlo >> 32) & 0xFFFF); stot[3] = (int)((tlo >> 48) & 0xFFFF);
        stot[4] = (int)(thi & 0xFFFF);         stot[5] = (int)((thi >> 16) & 0xFFFF);
        stot[6] = (int)((thi >> 32) & 0xFFFF); stot[7] = (int)((thi >> 48) & 0xFFFF);
        int s = 0;
        for (int bb = 0; bb < 8; ++bb) { sbases[bb] = s; s += stot[bb]; }
        meta[MH_C0] = stot[0];
        meta[MH_C1] = stot[1];
        for (int l = 0; l < 5; ++l) meta[MH_CNT + l]   = stot[2 + l];
        for (int l = 0; l < 5; ++l) meta[MH_PBASE + l] = sbases[2 + l] - sbases[2];
        meta[MH_P] = (sbases[7] - sbases[2]) + stot[7];
    }
    __syncthreads();

    unsigned long long exlo = inc_lo - clo, exhi = inc_hi - chi;
    int mypos[4], mypidx[4];
    #pragma unroll
    for (int q = 0; q < 4; ++q) {
        int i = i0 + q, b = myb[q];
        int pos;
        if (b < 4) { pos = (int)((exlo >> (16 * b)) & 0xFFFF); exlo += 1ull << (16 * b); }
        else       { pos = (int)((exhi >> (16 * (b - 4))) & 0xFFFF); exhi += 1ull << (16 * (b - 4)); }
        mypos[q] = pos;
        int pidx = -1;
        if (b == 0)      meta[OFF_K0N + pos] = i;
        else if (b == 1) meta[OFF_K1N + pos] = i;
        else {
            pidx = (sbases[b] - sbases[2]) + pos;
            meta[OFF_PLIST + pidx] = i;
            node2pidx[i] = pidx;
        }
        mypidx[q] = pidx;
    }
    #pragma unroll
    for (int q = 0; q < 4; ++q) deg[i0 + q] = 0;
    __syncthreads();

    int par[4];
    #pragma unroll
    for (int q = 0; q < 4; ++q) {
        int i = i0 + q; par[q] = parent[i];
        if (i != 0) atomicAdd(&deg[node2pidx[par[q]]], 1);
    }
    __syncthreads();

    int d0 = deg[i0], d1 = deg[i0 + 1], d2 = deg[i0 + 2], d3 = deg[i0 + 3];
    int s4 = d0 + d1 + d2 + d3;

    // int inclusive scan: wave-level shfl scan + wave-total combine
    int vi = s4;
    #pragma unroll
    for (int off = 1; off < 64; off <<= 1) {
        int u = __shfl_up(vi, off, 64);
        if (laneid >= off) vi += u;
    }
    if (laneid == 63) wint[wid] = vi;
    __syncthreads();
    int bint = 0;
    for (int w = 0; w < wid; ++w) bint += wint[w];
    int incl = vi + bint;

    int ex = incl - s4;
    int o0 = ex, o1 = ex + d0, o2 = o1 + d1, o3 = o2 + d2;
    deg[i0] = o0; deg[i0 + 1] = o1; deg[i0 + 2] = o2; deg[i0 + 3] = o3;
    meta[OFF_COFF + i0]     = o0;
    meta[OFF_COFF + i0 + 1] = o1;
    meta[OFF_COFF + i0 + 2] = o2;
    meta[OFF_COFF + i0 + 3] = o3;
    if (t == 1023) meta[OFF_COFF + N_PER] = o3 + d3;
    __syncthreads();

    #pragma unroll
    for (int q = 0; q < 4; ++q) {
        int i = i0 + q; if (i == 0) continue;
        int slot = atomicAdd(&deg[node2pidx[par[q]]], 1);
        int b = myb[q];
        if (b == 0)      meta[OFF_K0S + mypos[q]] = slot;
        else if (b == 1) meta[OFF_K1S + mypos[q]] = slot;
        else             meta[OFF_WSLOT + mypidx[q]] = slot;
    }

    // ---- weight tables ----
    // eaw/ebw: emb@node_w[:16] / emb@node_w[16:32]
    // la2/lb2: (emb@leaf_w1[:16])@leaf_w2 / (emb@leaf_w1[16:32])@leaf_w2
    //   (leaf MLP is LINEAR: leaf_h = la2[ta] + lb2[tb] + (b1@W2 + b2))
    {
        int hw = t >> 5, ln = t & 31;
        for (int v = hw; v < VOCAB; v += 32) {
            const float* ev = embedding + v * EMBED;
            float ea = 0.f, eb = 0.f, t1a = 0.f, t1b = 0.f;
            #pragma unroll
            for (int k = 0; k < EMBED; ++k) {
                float e = ev[k];
                ea  += e * node_w[k * HID + ln];
                eb  += e * node_w[(EMBED + k) * HID + ln];
                t1a += e * leaf_w1[k * HID + ln];
                t1b += e * leaf_w1[(EMBED + k) * HID + ln];
            }
            eaw_g[v * HID + ln] = ea;
            ebw_g[v * HID + ln] = eb;
            float a2 = 0.f, b2v = 0.f;
            #pragma unroll
            for (int k = 0; k < HID; ++k) {
                float w2 = leaf_w2[k * HID + ln];
                a2  += __shfl(t1a, k, 32) * w2;
                b2v += __shfl(t1b, k, 32) * w2;
            }
            la2[v * HID + ln] = a2;
            lb2[v * HID + ln] = b2v;
        }
        if (t < HID) {
            float c = leaf_b2[t];
            #pragma unroll
            for (int k = 0; k < HID; ++k) c += leaf_b1[k] * leaf_w2[k * HID + t];
            cc[t] = c;
        }
    }
}

// ---------------------------------------------------------------------------
// Leaf rows: h = cc + la2[ta] + lb2[tb]. Batch-4 per group => 4 independent
// tok->table latency chains in flight. Kept minimal for max occupancy.
// ---------------------------------------------------------------------------
__global__ __launch_bounds__(256) void leaf_kernel(
    const int* __restrict__ meta,
    const int* __restrict__ tok_a, const int* __restrict__ tok_b,
    const float* __restrict__ la2, const float* __restrict__ lb2,
    const float* __restrict__ cc,
    float* __restrict__ h)
{
    int lane = threadIdx.x & 31;
    int gid  = (blockIdx.x * blockDim.x + threadIdx.x) >> 5;
    int ngr  = (gridDim.x * blockDim.x) >> 5;

    float ccv = cc[lane];
    int c0 = meta[MH_C0];
    const int* K0N = meta + OFF_K0N;
    const int* K0S = meta + OFF_K0S;
    int tot = c0 * BATCH;

    for (int base = gid * 4; base < tot; base += ngr * 4) {
        int nq = tot - base; if (nq > 4) nq = 4;
        int ta[4], tb[4], slot[4], tree[4];
        #pragma unroll
        for (int q = 0; q < 4; ++q) {
            int i = base + (q < nq ? q : 0);
            int j = i >> 8; tree[q] = i & 255;
            int nd = K0N[j]; slot[q] = K0S[j];
            int gn = tree[q] * N_PER + nd;
            ta[q] = tok_a[gn]; tb[q] = tok_b[gn];
        }
        #pragma unroll
        for (int q = 0; q < 4; ++q) {
            if (q >= nq) break;
            h[(size_t)slot[q] * HSTR + tree[q] * HID + lane] =
                ccv + la2[ta[q] * HID + lane] + lb2[tb[q] * HID + lane];
        }
    }
}

// ---------------------------------------------------------------------------
// Ptr rows: h = ptr_b + fn[tree]@Wp[0:64] + lstm[tree,tt]@Wp[64:128]
// Standalone so its VGPR pressure doesn't cap leaf occupancy.
// ---------------------------------------------------------------------------
__global__ __launch_bounds__(256) void ptr_kernel(
    const int* __restrict__ meta, const int* __restrict__ ptr_time,
    const float* __restrict__ first_notes, const float* __restrict__ lstm_out,
    const float* __restrict__ ptr_w, const float* __restrict__ ptr_b,
    float* __restrict__ h)
{
    int lane = threadIdx.x & 31;
    int gid  = (blockIdx.x * blockDim.x + threadIdx.x) >> 5;
    int ngr  = (gridDim.x * blockDim.x) >> 5;

    float pb = ptr_b[lane];
    int c1 = meta[MH_C1];
    const int* K1N = meta + OFF_K1N;
    const int* K1S = meta + OFF_K1S;
    int tot = c1 * BATCH;

    for (int i = gid; i < tot; i += ngr) {
        int j = i >> 8, tree = i & 255;
        int node = K1N[j], slot = K1S[j];
        int gn = tree * N_PER + node;
        int tt = ptr_time[gn];
        const float* fn = first_notes + (size_t)tree * NOTE;
        const float* lo = lstm_out + ((size_t)tree * T_LEN + tt) * LSTM_D;
        float v = pb;
        #pragma unroll
        for (int k = 0; k < NOTE; ++k)   v += fn[k] * ptr_w[k * HID + lane];
        #pragma unroll
        for (int k = 0; k < LSTM_D; ++k) v += lo[k] * ptr_w[(NOTE + k) * HID + lane];
        h[(size_t)slot * HSTR + tree * HID + lane] = v;
    }
}

// ---------------------------------------------------------------------------
// Level pass (lvl = 0..4 for heights 1..5). Batch-4 per group: consecutive
// items share the parent (adjacent trees) ~7/8 of the time -> fast path with
// one metadata fetch and contiguous 512B children reads, 4-way ILP.
// ---------------------------------------------------------------------------
__global__ __launch_bounds__(256) void level_kernel(
    const int* __restrict__ meta,
    const int* __restrict__ tok_a, const int* __restrict__ tok_b,
    const float* __restrict__ eaw_g, const float* __restrict__ ebw_g,
    const float* __restrict__ node_w, const float* __restrict__ node_b,
    float* __restrict__ h, int lvl)
{
    int cnt = meta[MH_CNT + lvl];
    if (cnt == 0) return;
    int pb  = meta[MH_PBASE + lvl];
    const int* PL = meta + OFF_PLIST;
    const int* WS = meta + OFF_WSLOT;
    const int* CO = meta + OFF_COFF;

    int lane = threadIdx.x & 31;
    int gid  = (blockIdx.x * blockDim.x + threadIdx.x) >> 5;
    int ngr  = (gridDim.x * blockDim.x) >> 5;

    float wc[HID];
    #pragma unroll
    for (int k = 0; k < HID; ++k) wc[k] = node_w[(2 * EMBED + k) * HID + lane];
    float nb = node_b[lane];

    int perchunk = cnt << 5;             // parents * 32 trees
    int tot = cnt * BATCH;

    for (int base = gid * 4; base < tot; base += ngr * 4) {
        int nq = tot - base; if (nq > 4) nq = 4;
        int pidx[4], tree[4];
        #pragma unroll
        for (int q = 0; q < 4; ++q) {
            int i = base + (q < nq ? q : 0);
            int tchunk = i / perchunk;
            int r = i - tchunk * perchunk;
            tree[q] = (tchunk << 5) + (r & 31);
            pidx[q] = pb + (r >> 5);
        }
        int node[4], wsl[4], e0[4], e1[4];
        #pragma unroll
        for (int q = 0; q < 4; ++q) {
            node[q] = PL[pidx[q]]; wsl[q] = WS[pidx[q]];
            e0[q] = CO[pidx[q]];  e1[q] = CO[pidx[q] + 1];
        }
        int ta[4], tb[4];
        #pragma unroll
        for (int q = 0; q < 4; ++q) {
            int gn = tree[q] * N_PER + node[q];
            ta[q] = tok_a[gn]; tb[q] = tok_b[gn];
        }
        float cs[4] = {0.f, 0.f, 0.f, 0.f};
        if (nq == 4 && pidx[0] == pidx[3]) {
            // same parent, 4 adjacent trees: contiguous 512B per child row
            const float* hb = h + (size_t)tree[0] * HID + lane;
            int en = e1[0];
            for (int c = e0[0]; c < en; ++c) {
                size_t o = (size_t)c * HSTR;
                cs[0] += hb[o];
                cs[1] += hb[o + HID];
                cs[2] += hb[o + 2 * HID];
                cs[3] += hb[o + 3 * HID];
            }
        } else {
            #pragma unroll
            for (int q = 0; q < 4; ++q) {
                if (q >= nq) break;
                const float* hb = h + (size_t)tree[q] * HID + lane;
                float s = 0.f;
                for (int c = e0[q]; c < e1[q]; ++c) s += hb[(size_t)c * HSTR];
                cs[q] = s;
            }
        }
        #pragma unroll
        for (int q = 0; q < 4; ++q) {
            if (q >= nq) break;
            float v = nb + eaw_g[ta[q] * HID + lane] + ebw_g[tb[q] * HID + lane];
            #pragma unroll
            for (int k = 0; k < HID; ++k) v += __shfl(cs[q], k, 32) * wc[k];
            v = fmaxf(v, 0.f);
            h[(size_t)wsl[q] * HSTR + tree[q] * HID + lane] = v;
        }
    }
}

// ---------------------------------------------------------------------------
// Fused root gather + head: one block per tree. 16 groups sum root-children
// rows (strided), LDS-reduce, group 0 runs the node op + FF head.
// Removes rootsum memset + atomics + one dispatch.
// ---------------------------------------------------------------------------
__global__ __launch_bounds__(512) void root_final_kernel(
    const int* __restrict__ meta,
    const int* __restrict__ tok_a, const int* __restrict__ tok_b,
    const float* __restrict__ eaw_g, const float* __restrict__ ebw_g,
    const float* __restrict__ h,
    const float* __restrict__ node_w, const float* __restrict__ node_b,
    const float* __restrict__ ff_w1, const float* __restrict__ ff_b1,
    const float* __restrict__ ff_w2, const float* __restrict__ ff_b2,
    const float* __restrict__ tail_w, const float* __restrict__ tail_b,
    float* __restrict__ out)
{
    __shared__ float part[16][33];   // +1 pad: conflict-free group writes
    int tree = blockIdx.x;
    int lane = threadIdx.x & 31;
    int g    = threadIdx.x >> 5;     // 0..15

    const int* CO = meta + OFF_COFF;
    int P = meta[MH_P];
    int e = CO[P - 1], e1 = CO[P];

    const float* hb = h + (size_t)tree * HID + lane;
    float s = 0.f;
    for (int c = e + g; c < e1; c += 16)
        s += hb[(size_t)c * HSTR];
    part[g][lane] = s;
    __syncthreads();

    if (g == 0) {
        float csum = part[0][lane];
        #pragma unroll
        for (int k = 1; k < 16; ++k) csum += part[k][lane];

        int gn = tree * N_PER;   // root = node 0
        int ta = tok_a[gn], tb = tok_b[gn];
        float v = node_b[lane] + eaw_g[ta * HID + lane] + ebw_g[tb * HID + lane];
        #pragma unroll
        for (int k = 0; k < HID; ++k)
            v += __shfl(csum, k, 32) * node_w[(2 * EMBED + k) * HID + lane];
        v = fmaxf(v, 0.f);

        float f1 = ff_b1[lane];
        #pragma unroll
        for (int k = 0; k < HID; ++k) f1 += __shfl(v, k, 32) * ff_w1[k * HID + lane];
        float f2 = ff_b2[lane];
        #pragma unroll
        for (int k = 0; k < HID; ++k) f2 += __shfl(f1, k, 32) * ff_w2[k * HID + lane];

        float c2 = f2 * tail_w[lane];
        #pragma unroll
        for (int off = 16; off > 0; off >>= 1) c2 += __shfl_down(c2, off, 32);
        if (lane == 0) out[tree] = c2 + tail_b[0];
    }
}

extern "C" void kernel_launch(void* const* d_in, const int* in_sizes, int n_in,
                              void* d_out, int out_size, void* d_ws, size_t ws_size,
                              hipStream_t stream) {
    const int*   kind        = (const int*)d_in[0];
    const int*   height      = (const int*)d_in[1];
    const int*   parent      = (const int*)d_in[2];
    const int*   tok_a       = (const int*)d_in[3];
    const int*   tok_b       = (const int*)d_in[4];
    const int*   ptr_time    = (const int*)d_in[5];
    const float* first_notes = (const float*)d_in[6];
    const float* lstm_out    = (const float*)d_in[7];
    const float* embedding   = (const float*)d_in[8];
    const float* leaf_w1     = (const float*)d_in[9];
    const float* leaf_b1     = (const float*)d_in[10];
    const float* leaf_w2     = (const float*)d_in[11];
    const float* leaf_b2     = (const float*)d_in[12];
    const float* node_w      = (const float*)d_in[13];
    const float* node_b      = (const float*)d_in[14];
    const float* ptr_w       = (const float*)d_in[15];
    const float* ptr_b       = (const float*)d_in[16];
    const float* ff_w1       = (const float*)d_in[17];
    const float* ff_b1       = (const float*)d_in[18];
    const float* ff_w2       = (const float*)d_in[19];
    const float* ff_b2       = (const float*)d_in[20];
    const float* tail_w      = (const float*)d_in[21];
    const float* tail_b      = (const float*)d_in[22];

    char* ws = (char*)d_ws;
    int*   meta    = (int*)ws;
    float* eaw_g   = (float*)(ws + EAW_OFF);
    float* ebw_g   = (float*)(ws + EBW_OFF);
    float* la2     = (float*)(ws + LA2_OFF);
    float* lb2     = (float*)(ws + LB2_OFF);
    float* cc      = (float*)(ws + CC_OFF);
    float* h       = (float*)(ws + H_OFF);

    build_structure<<<1, 1024, 0, stream>>>(
        kind, height, parent, meta,
        embedding, leaf_w1, leaf_b1, leaf_w2, leaf_b2, node_w,
        eaw_g, ebw_g, la2, lb2, cc);

    leaf_kernel<<<2048, 256, 0, stream>>>(
        meta, tok_a, tok_b, la2, lb2, cc, h);

    ptr_kernel<<<512, 256, 0, stream>>>(
        meta, ptr_time, first_notes, lstm_out, ptr_w, ptr_b, h);

    for (int lvl = 0; lvl < 5; ++lvl) {
        level_kernel<<<2048, 256, 0, stream>>>(
            meta, tok_a, tok_b, eaw_g, ebw_g, node_w, node_b, h, lvl);
    }

    root_final_kernel<<<BATCH, 512, 0, stream>>>(
        meta, tok_a, tok_b, eaw_g, ebw_g, h, node_w, node_b,
        ff_w1, ff_b1, ff_w2, ff_b2, tail_w, tail_b, (float*)d_out);
}